// Round 1
// baseline (37.614 us; speedup 1.0000x reference)
//
#include <hip/hip_runtime.h>

#define D_MODEL 4096
#define NN      4403      // selected neurons
#define NB      64        // batch
#define BN      64        // neurons per block (4 waves x 16)
#define BK      128       // K per LDS step
#define KCH     512       // K-chunk per block
#define KSTEPS  (KCH / BK)        // 4
#define KSPLIT  (D_MODEL / KCH)   // 8
#define LDK     (BK + 8)          // padded row: 136 elems -> 272 B (breaks bank conflicts)

using f32x4  = __attribute__((ext_vector_type(4))) float;
using bf16x8 = __attribute__((ext_vector_type(8))) short;
using u16x8  = __attribute__((ext_vector_type(8))) unsigned short;

__device__ __forceinline__ unsigned short f2bf(float f) {
    unsigned int u = __float_as_uint(f);
    u += 0x7FFFu + ((u >> 16) & 1u);   // round-to-nearest-even
    return (unsigned short)(u >> 16);
}

__device__ __forceinline__ void store8(unsigned short* d, f32x4 a, f32x4 b) {
    u16x8 v;
    v[0] = f2bf(a[0]); v[1] = f2bf(a[1]); v[2] = f2bf(a[2]); v[3] = f2bf(a[3]);
    v[4] = f2bf(b[0]); v[5] = f2bf(b[1]); v[6] = f2bf(b[2]); v[7] = f2bf(b[3]);
    *(u16x8*)d = v;   // 16 B ds_write_b128 (offsets are 16B-aligned by construction)
}

__global__ __launch_bounds__(256, 2)
void gather_gemm_bf16(const float* __restrict__ X,
                      const float* __restrict__ W,
                      const int*   __restrict__ idx,
                      float* __restrict__ out)
{
    __shared__ __align__(16) unsigned short Xs[2][64 * LDK];
    __shared__ __align__(16) unsigned short Ws[2][64 * LDK];

    const int tid   = threadIdx.x;
    const int wave  = tid >> 6;
    const int lane  = tid & 63;
    const int n0    = blockIdx.x * BN;
    const int kbase = blockIdx.y * KCH;

    // staging: 16 threads per row, 8 consecutive floats each -> fully coalesced
    const int srow = tid >> 4;         // 0..15 (row within a 16-row pass)
    const int kq   = (tid & 15) * 8;   // element offset within BK

    const float* xp[4];
    const float* wp[4];
#pragma unroll
    for (int p = 0; p < 4; ++p) {
        int r = p * 16 + srow;                 // 0..63
        int n = n0 + r;
        int wrow = (n < NN) ? idx[n] : 0;      // clamp: results discarded in epilogue
        xp[p] = X + (size_t)r * D_MODEL + kbase + kq;
        wp[p] = W + (size_t)wrow * D_MODEL + kbase + kq;
    }

    f32x4 xr[4][2], wr[4][2];

    // ---- load K-step 0 ----
#pragma unroll
    for (int p = 0; p < 4; ++p) {
        xr[p][0] = *(const f32x4*)(xp[p] + 0);
        xr[p][1] = *(const f32x4*)(xp[p] + 4);
        wr[p][0] = *(const f32x4*)(wp[p] + 0);
        wr[p][1] = *(const f32x4*)(wp[p] + 4);
    }

    f32x4 acc[4];
#pragma unroll
    for (int m = 0; m < 4; ++m) acc[m] = (f32x4){0.f, 0.f, 0.f, 0.f};

    // ---- cvt + write buffer 0 ----
#pragma unroll
    for (int p = 0; p < 4; ++p) {
        int r = p * 16 + srow;
        store8(&Xs[0][r * LDK + kq], xr[p][0], xr[p][1]);
        store8(&Ws[0][r * LDK + kq], wr[p][0], wr[p][1]);
    }
    __syncthreads();

    const int fr = lane & 15;          // row/col within 16-tile
    const int fk = (lane >> 4) * 8;    // k offset of fragment

    int buf = 0;
    for (int t = 0; t < KSTEPS; ++t) {
        // prefetch next K-step into registers (overlaps with MFMA below)
        if (t + 1 < KSTEPS) {
#pragma unroll
            for (int p = 0; p < 4; ++p) {
                xr[p][0] = *(const f32x4*)(xp[p] + (t + 1) * BK + 0);
                xr[p][1] = *(const f32x4*)(xp[p] + (t + 1) * BK + 4);
                wr[p][0] = *(const f32x4*)(wp[p] + (t + 1) * BK + 0);
                wr[p][1] = *(const f32x4*)(wp[p] + (t + 1) * BK + 4);
            }
        }
        // compute current buffer: wave owns 16 neurons, all 64 batch rows
        const unsigned short* wrp = &Ws[buf][(wave * 16 + fr) * LDK + fk];
#pragma unroll
        for (int kk = 0; kk < BK / 32; ++kk) {
            bf16x8 bfrag = *(const bf16x8*)(wrp + kk * 32);
#pragma unroll
            for (int m = 0; m < 4; ++m) {
                bf16x8 afrag = *(const bf16x8*)(&Xs[buf][(m * 16 + fr) * LDK + kk * 32 + fk]);
                acc[m] = __builtin_amdgcn_mfma_f32_16x16x32_bf16(afrag, bfrag, acc[m], 0, 0, 0);
            }
        }
        if (t + 1 < KSTEPS) {
#pragma unroll
            for (int p = 0; p < 4; ++p) {
                int r = p * 16 + srow;
                store8(&Xs[buf ^ 1][r * LDK + kq], xr[p][0], xr[p][1]);
                store8(&Ws[buf ^ 1][r * LDK + kq], wr[p][0], wr[p][1]);
            }
            __syncthreads();   // one barrier per step: next step reads buf^1
            buf ^= 1;
        }
    }

    // epilogue: C/D layout col = lane&15 (neuron), row = (lane>>4)*4 + reg (batch)
    const int ncol = n0 + wave * 16 + fr;
    if (ncol < NN) {
#pragma unroll
        for (int m = 0; m < 4; ++m) {
            int brow = m * 16 + (lane >> 4) * 4;
#pragma unroll
            for (int r = 0; r < 4; ++r) {
                atomicAdd(&out[(size_t)(brow + r) * NN + ncol], acc[m][r]);
            }
        }
    }
}

extern "C" void kernel_launch(void* const* d_in, const int* in_sizes, int n_in,
                              void* d_out, int out_size, void* d_ws, size_t ws_size,
                              hipStream_t stream) {
    const float* X   = (const float*)d_in[0];   // [64,1,4096] f32
    const float* W   = (const float*)d_in[1];   // [11008,4096] f32
    const int*   idx = (const int*)d_in[2];     // [4403] i32
    float* out = (float*)d_out;                 // [64,1,4403] f32

    hipMemsetAsync(d_out, 0, (size_t)out_size * sizeof(float), stream);

    dim3 grid((NN + BN - 1) / BN, KSPLIT, 1);   // 69 x 8
    gather_gemm_bf16<<<grid, 256, 0, stream>>>(X, W, idx, out);
}

// Round 2
// 27.277 us; speedup vs baseline: 1.3790x; 1.3790x over previous
//
#include <hip/hip_runtime.h>

#define D_MODEL 4096
#define NN      4403      // selected neurons
#define NB      64        // batch
#define BN      64        // neurons per block (4 waves x 16)
#define BK      128       // K per LDS step
#define KCH     512       // K-chunk per block
#define KSTEPS  (KCH / BK)        // 4
#define KSPLIT  (D_MODEL / KCH)   // 8
#define LDK     (BK + 8)          // padded row: 136 elems -> 272 B (breaks bank conflicts)
#define OUT_ELEMS (NB * NN)       // 281792
#define WS_NEEDED ((size_t)KSPLIT * OUT_ELEMS * 4)

using f32x4  = __attribute__((ext_vector_type(4))) float;
using bf16x8 = __attribute__((ext_vector_type(8))) short;
using u16x8  = __attribute__((ext_vector_type(8))) unsigned short;

__device__ __forceinline__ unsigned short f2bf(float f) {
    unsigned int u = __float_as_uint(f);
    u += 0x7FFFu + ((u >> 16) & 1u);   // round-to-nearest-even
    return (unsigned short)(u >> 16);
}

__device__ __forceinline__ void store8(unsigned short* d, f32x4 a, f32x4 b) {
    u16x8 v;
    v[0] = f2bf(a[0]); v[1] = f2bf(a[1]); v[2] = f2bf(a[2]); v[3] = f2bf(a[3]);
    v[4] = f2bf(b[0]); v[5] = f2bf(b[1]); v[6] = f2bf(b[2]); v[7] = f2bf(b[3]);
    *(u16x8*)d = v;   // 16 B ds_write_b128
}

template <bool ATOMIC>
__global__ __launch_bounds__(256, 2)
void gather_gemm_bf16(const float* __restrict__ X,
                      const float* __restrict__ W,
                      const int*   __restrict__ idx,
                      float* __restrict__ out)   // partial base (or out if ATOMIC)
{
    __shared__ __align__(16) unsigned short Xs[2][64 * LDK];
    __shared__ __align__(16) unsigned short Ws[2][64 * LDK];

    const int tid   = threadIdx.x;
    const int wave  = tid >> 6;
    const int lane  = tid & 63;
    const int n0    = blockIdx.x * BN;
    const int kbase = blockIdx.y * KCH;

    const int srow = tid >> 4;         // 0..15
    const int kq   = (tid & 15) * 8;   // element offset within BK

    const float* xp[4];
    const float* wp[4];
#pragma unroll
    for (int p = 0; p < 4; ++p) {
        int r = p * 16 + srow;
        int n = n0 + r;
        int wrow = (n < NN) ? idx[n] : 0;
        xp[p] = X + (size_t)r * D_MODEL + kbase + kq;
        wp[p] = W + (size_t)wrow * D_MODEL + kbase + kq;
    }

    f32x4 xr[4][2], wr[4][2];
#pragma unroll
    for (int p = 0; p < 4; ++p) {
        xr[p][0] = *(const f32x4*)(xp[p] + 0);
        xr[p][1] = *(const f32x4*)(xp[p] + 4);
        wr[p][0] = *(const f32x4*)(wp[p] + 0);
        wr[p][1] = *(const f32x4*)(wp[p] + 4);
    }

    f32x4 acc[4];
#pragma unroll
    for (int m = 0; m < 4; ++m) acc[m] = (f32x4){0.f, 0.f, 0.f, 0.f};

#pragma unroll
    for (int p = 0; p < 4; ++p) {
        int r = p * 16 + srow;
        store8(&Xs[0][r * LDK + kq], xr[p][0], xr[p][1]);
        store8(&Ws[0][r * LDK + kq], wr[p][0], wr[p][1]);
    }
    __syncthreads();

    const int fr = lane & 15;
    const int fk = (lane >> 4) * 8;

    int buf = 0;
    for (int t = 0; t < KSTEPS; ++t) {
        if (t + 1 < KSTEPS) {
#pragma unroll
            for (int p = 0; p < 4; ++p) {
                xr[p][0] = *(const f32x4*)(xp[p] + (t + 1) * BK + 0);
                xr[p][1] = *(const f32x4*)(xp[p] + (t + 1) * BK + 4);
                wr[p][0] = *(const f32x4*)(wp[p] + (t + 1) * BK + 0);
                wr[p][1] = *(const f32x4*)(wp[p] + (t + 1) * BK + 4);
            }
        }
        const unsigned short* wrp = &Ws[buf][(wave * 16 + fr) * LDK + fk];
#pragma unroll
        for (int kk = 0; kk < BK / 32; ++kk) {
            bf16x8 bfrag = *(const bf16x8*)(wrp + kk * 32);
#pragma unroll
            for (int m = 0; m < 4; ++m) {
                bf16x8 afrag = *(const bf16x8*)(&Xs[buf][(m * 16 + fr) * LDK + kk * 32 + fk]);
                acc[m] = __builtin_amdgcn_mfma_f32_16x16x32_bf16(afrag, bfrag, acc[m], 0, 0, 0);
            }
        }
        if (t + 1 < KSTEPS) {
#pragma unroll
            for (int p = 0; p < 4; ++p) {
                int r = p * 16 + srow;
                store8(&Xs[buf ^ 1][r * LDK + kq], xr[p][0], xr[p][1]);
                store8(&Ws[buf ^ 1][r * LDK + kq], wr[p][0], wr[p][1]);
            }
            __syncthreads();
            buf ^= 1;
        }
    }

    // epilogue: C/D layout col = lane&15 (neuron), row = (lane>>4)*4 + reg (batch)
    const int ncol = n0 + wave * 16 + fr;
    if (ncol < NN) {
        float* base = ATOMIC ? out : out + (size_t)blockIdx.y * OUT_ELEMS;
#pragma unroll
        for (int m = 0; m < 4; ++m) {
            int brow = m * 16 + (lane >> 4) * 4;
#pragma unroll
            for (int r = 0; r < 4; ++r) {
                if (ATOMIC)
                    atomicAdd(&base[(size_t)(brow + r) * NN + ncol], acc[m][r]);
                else
                    base[(size_t)(brow + r) * NN + ncol] = acc[m][r];
            }
        }
    }
}

// out[i] = sum_s partial[s][i]   (fully coalesced float4 both ways)
__global__ __launch_bounds__(256)
void reduce_splitk(const float* __restrict__ p, float* __restrict__ out) {
    const int i = blockIdx.x * 256 + threadIdx.x;        // float4 index
    const int n4 = OUT_ELEMS / 4;                        // 70448
    if (i >= n4) return;
    const f32x4* p4 = (const f32x4*)p;
    f32x4 a = p4[i];
#pragma unroll
    for (int s = 1; s < KSPLIT; ++s) a += p4[(size_t)s * n4 + i];
    ((f32x4*)out)[i] = a;
}

extern "C" void kernel_launch(void* const* d_in, const int* in_sizes, int n_in,
                              void* d_out, int out_size, void* d_ws, size_t ws_size,
                              hipStream_t stream) {
    const float* X   = (const float*)d_in[0];   // [64,1,4096] f32
    const float* W   = (const float*)d_in[1];   // [11008,4096] f32
    const int*   idx = (const int*)d_in[2];     // [4403] i32
    float* out = (float*)d_out;                 // [64,1,4403] f32

    dim3 grid((NN + BN - 1) / BN, KSPLIT, 1);   // 69 x 8

    if (ws_size >= WS_NEEDED) {
        float* partial = (float*)d_ws;
        gather_gemm_bf16<false><<<grid, 256, 0, stream>>>(X, W, idx, partial);
        int n4 = OUT_ELEMS / 4;
        reduce_splitk<<<(n4 + 255) / 256, 256, 0, stream>>>(partial, out);
    } else {
        hipMemsetAsync(d_out, 0, (size_t)out_size * sizeof(float), stream);
        gather_gemm_bf16<true><<<grid, 256, 0, stream>>>(X, W, idx, out);
    }
}